// Round 13
// baseline (605.916 us; speedup 1.0000x reference)
//
#include <hip/hip_runtime.h>
#include <hip/hip_bf16.h>

typedef __attribute__((ext_vector_type(8))) short bf16x8;
typedef __attribute__((ext_vector_type(4))) float f32x4;

#define MFMA_BF16 __builtin_amdgcn_mfma_f32_16x16x32_bf16

#define GLDS16(gp, lp)                                                        \
  __builtin_amdgcn_global_load_lds(                                           \
      (const __attribute__((address_space(1))) void*)(gp),                    \
      (__attribute__((address_space(3))) void*)(lp), 16, 0, 0)

__device__ __forceinline__ unsigned pk2(float a, float b) {
  __hip_bfloat162 t = __float22bfloat162_rn(make_float2(a, b));
  return *reinterpret_cast<unsigned*>(&t);
}
__device__ __forceinline__ unsigned short f2bf_hw(float f) {
  __hip_bfloat16 h = __float2bfloat16(f);
  return *reinterpret_cast<unsigned short*>(&h);
}
__device__ __forceinline__ float tanh_f(float x) {
  return 1.f - 2.f * __builtin_amdgcn_rcpf(1.f + __expf(2.f * x));
}

// ---------------------------------------------------------------------------
// k0: one-time weight conversion (= R11).
// ---------------------------------------------------------------------------
__global__ void k0_conv(const float* __restrict__ W0, const float* __restrict__ Wfw,
                        const float* __restrict__ Wbw, unsigned short* __restrict__ wfrag,
                        unsigned short* __restrict__ wlstm) {
  int gid = blockIdx.x * 256 + threadIdx.x;
  if (gid < 4096) {
    int f = gid >> 6, l = gid & 63;
    int k0 = (f >> 2) * 32 + ((l >> 4) << 3);
    int n = (f & 3) * 16 + (l & 15);
    bf16x8 v;
#pragma unroll
    for (int j = 0; j < 8; ++j) v[j] = (short)f2bf_hw(W0[(k0 + j) * 64 + n]);
    *(bf16x8*)(wfrag + gid * 8) = v;
  } else if (gid < 12288) {
    int g2 = gid - 4096;
    const float* W = (g2 < 4096) ? Wfw : Wbw;
    int f = (g2 & 4095) >> 6, l = g2 & 63;
    int wv = f >> 4, gate = (f >> 2) & 3, kf = f & 3;
    int col = gate * 64 + wv * 16 + (l & 15);
    int kr = kf * 32 + ((l >> 4) << 3);
    bf16x8 v;
#pragma unroll
    for (int j = 0; j < 8; ++j) v[j] = (short)f2bf_hw(W[(kr + j) * 256 + col]);
    *(bf16x8*)(wlstm + g2 * 8) = v;
  }
}

// ---------------------------------------------------------------------------
// K1: R8/R11 structure, body repeated 3x IN-KERNEL for rocprof visibility
// (each rep is the identical, idempotent computation).
// ---------------------------------------------------------------------------
__global__ __launch_bounds__(256, 3) void k_dense_ln(
    const float* __restrict__ obs, const unsigned short* __restrict__ wfrag,
    const float* __restrict__ b0, const float* __restrict__ gam,
    const float* __restrict__ bet, unsigned short* __restrict__ xout) {
  __shared__ __align__(16) char lds[49152];  // 3 x 16 KB
  const int tid = threadIdx.x, w = tid >> 6, l = tid & 63;
  const int g = l >> 4, c = l & 15;
  const long blk64 = (long)blockIdx.x * 64;
  const long rb = blk64 + w * 16;

  float b0v[4], gv[4], bv[4];
#pragma unroll
  for (int nt = 0; nt < 4; ++nt) {
    int col = nt * 16 + c;
    b0v[nt] = b0[col]; gv[nt] = gam[col]; bv[nt] = bet[col];
  }
  const unsigned short* wfl = wfrag + l * 8;
  const char* gB = (const char*)obs + blk64 * 2048;
  const int rlo = w * 4 + g;

#define K1_STAGE(q)                                                           \
  {                                                                           \
    _Pragma("unroll") for (int i = 0; i < 4; ++i) {                           \
      int row_ = i * 16 + rlo;                                                \
      const char* gp_ = gB + (long)row_ * 2048 + (q) * 256 +                  \
                        (long)((c ^ rlo) * 16);                               \
      char* lp_ = lds + ((q) % 3) * 16384 + (i * 4096 + (w * 64 + l) * 16);   \
      GLDS16(gp_, lp_);                                                       \
    }                                                                         \
  }

#pragma unroll 1
  for (int rep = 0; rep < 3; ++rep) {
    asm volatile("s_waitcnt vmcnt(0)" ::: "memory");
    __builtin_amdgcn_s_barrier();   // prior rep fully done (LDS reuse safe)
    __builtin_amdgcn_sched_barrier(0);

    K1_STAGE(0);
    K1_STAGE(1);
    K1_STAGE(2);

    f32x4 acc[4];
#pragma unroll
    for (int nt = 0; nt < 4; ++nt) acc[nt] = (f32x4){0.f, 0.f, 0.f, 0.f};

#pragma unroll
    for (int q = 0; q < 8; ++q) {
      constexpr int VW[8] = {8, 16, 24, 24, 24, 24, 20, 16};
      asm volatile("s_waitcnt vmcnt(%0)" :: "i"(VW[q]) : "memory");
      __builtin_amdgcn_s_barrier();
      __builtin_amdgcn_sched_barrier(0);

      const char* rowb = lds + (q % 3) * 16384 + (w * 16 + c) * 256;
#pragma unroll
      for (int kf = 0; kf < 2; ++kf) {
        int fb = (q * 2 + kf) * 4;
        bf16x8 B0 = *(const bf16x8*)(wfl + (fb + 0) * 512);
        bf16x8 B1 = *(const bf16x8*)(wfl + (fb + 1) * 512);
        bf16x8 B2 = *(const bf16x8*)(wfl + (fb + 2) * 512);
        bf16x8 B3 = *(const bf16x8*)(wfl + (fb + 3) * 512);
        int u0 = kf * 8 + g * 2;
        float4 f0 = *(const float4*)(rowb + ((u0 + 0) ^ c) * 16);
        float4 f1 = *(const float4*)(rowb + ((u0 + 1) ^ c) * 16);
        union { bf16x8 v; unsigned u[4]; } af;
        af.u[0] = pk2(f0.x, f0.y); af.u[1] = pk2(f0.z, f0.w);
        af.u[2] = pk2(f1.x, f1.y); af.u[3] = pk2(f1.z, f1.w);
        acc[0] = MFMA_BF16(af.v, B0, acc[0], 0, 0, 0);
        acc[1] = MFMA_BF16(af.v, B1, acc[1], 0, 0, 0);
        acc[2] = MFMA_BF16(af.v, B2, acc[2], 0, 0, 0);
        acc[3] = MFMA_BF16(af.v, B3, acc[3], 0, 0, 0);
      }
      if (q < 5) {
        __builtin_amdgcn_s_barrier();
        __builtin_amdgcn_sched_barrier(0);
        K1_STAGE(q + 3);
      }
    }

    float vv[4][4], s1[4], s2[4];
#pragma unroll
    for (int r = 0; r < 4; ++r) { s1[r] = 0.f; s2[r] = 0.f; }
#pragma unroll
    for (int nt = 0; nt < 4; ++nt)
#pragma unroll
      for (int r = 0; r < 4; ++r) {
        float val = acc[nt][r] + b0v[nt];
        vv[nt][r] = val; s1[r] += val; s2[r] += val * val;
      }
#pragma unroll
    for (int r = 0; r < 4; ++r) {
#pragma unroll
      for (int m = 1; m <= 8; m <<= 1) {
        s1[r] += __shfl_xor(s1[r], m);
        s2[r] += __shfl_xor(s2[r], m);
      }
    }
    unsigned short* xw = (unsigned short*)lds + w * 1024;
#pragma unroll
    for (int r = 0; r < 4; ++r) {
      float mu = s1[r] * 0.015625f;
      float var = s2[r] * 0.015625f - mu * mu;
      float inv = rsqrtf(var + 1e-12f);
      int row = g * 4 + r;
#pragma unroll
      for (int nt = 0; nt < 4; ++nt) {
        float xn = (vv[nt][r] - mu) * inv * gv[nt] + bv[nt];
        xw[(row * 64 + nt * 16 + c) ^ (g << 3)] = f2bf_hw(fmaxf(xn, 0.f));
      }
    }
#pragma unroll
    for (int m2 = 0; m2 < 2; ++m2) {
      int m = m2 * 64 + l;
      int row = m >> 3, u8 = m & 7;
      bf16x8 v = *(const bf16x8*)(xw + ((row * 64 + u8 * 8) ^ ((row >> 2) << 3)));
      *(bf16x8*)(xout + (rb + row) * 64 + u8 * 8) = v;
    }
  }
}

// ---------------------------------------------------------------------------
// K2: EXACTLY R11's inner structure (best K2: 512 blocks, 16 seq, ring of 8
// slots x 2KB, proj->LDS), repeated 8x IN-KERNEL for rocprof visibility.
// ---------------------------------------------------------------------------
__global__ __launch_bounds__(256, 2) void k_lstm(
    const unsigned short* __restrict__ x, const unsigned short* __restrict__ wlstm,
    const float* __restrict__ bfw, const float* __restrict__ bbw,
    const float* __restrict__ Wc, const float* __restrict__ bc,
    float* __restrict__ out) {
  __shared__ __align__(16) char xr[8 * 2048];
  __shared__ unsigned short hl[2 * 1024];
  __shared__ float pl[16 * 32 * 8];
  const int tid = threadIdx.x, w = tid >> 6, l = tid & 63;
  const int g = l >> 4, c = l & 15;
  const int dir = blockIdx.x >> 8;
  const int sq = (blockIdx.x & 255) * 16;
  const float* bias = dir ? bbw : bfw;

  bf16x8 Bf[4][4];
  const unsigned short* wl = wlstm + ((long)dir * 4096 + w * 16 * 64) * 8;
#pragma unroll
  for (int gate = 0; gate < 4; ++gate)
#pragma unroll
    for (int kf = 0; kf < 4; ++kf)
      Bf[gate][kf] = *(const bf16x8*)(wl + ((gate * 4 + kf) * 64 + l) * 8);
  float bz[4];
#pragma unroll
  for (int gate = 0; gate < 4; ++gate) bz[gate] = bias[gate * 64 + w * 16 + c];

  bf16x8 Pc[2];
#pragma unroll
  for (int kf = 0; kf < 2; ++kf)
#pragma unroll
    for (int j = 0; j < 8; ++j) Pc[kf][j] = 0;
  float bcv = 0.f;
  if (c < 8) {
#pragma unroll
    for (int kf = 0; kf < 2; ++kf)
#pragma unroll
      for (int j = 0; j < 8; ++j)
        Pc[kf][j] = (short)f2bf_hw(Wc[(kf * 32 + g * 8 + j) * 8 + c]);
    bcv = bc[c];
  }

  const int ss = l >> 3, sc = l & 7;
#define K2_STAGE(tt)                                                          \
  {                                                                           \
    int te_ = dir ? 31 - (tt) : (tt);                                         \
    _Pragma("unroll") for (int p_ = 0; p_ < 2; ++p_) {                        \
      int s_ = p_ * 8 + ss;                                                   \
      const char* gp_ = (const char*)x +                                      \
          ((long)(sq + s_) * 32 + te_) * 128 + (long)(sc ^ (s_ & 7)) * 16;    \
      char* lp_ = xr + ((tt) & 7) * 2048 + p_ * 1024;                         \
      GLDS16(gp_, lp_);                                                       \
    }                                                                         \
  }

  const int hq = w >> 1;
  const int hgp = ((w & 1) * 2 + (c >> 3)) * 16;
  const int hlo = c & 7;

#pragma unroll 1
  for (int rep = 0; rep < 8; ++rep) {
    asm volatile("s_waitcnt vmcnt(0)" ::: "memory");
    __builtin_amdgcn_s_barrier();   // prior rep (incl. pl flush reads) done
    __builtin_amdgcn_sched_barrier(0);

    K2_STAGE(w);
    K2_STAGE(w + 4);

    for (int i = tid; i < 1024; i += 256) ((unsigned*)hl)[i] = 0u;
    float cs[4] = {0.f, 0.f, 0.f, 0.f};

    if (w < 2) asm volatile("s_waitcnt vmcnt(2)" ::: "memory");
    asm volatile("s_waitcnt lgkmcnt(0)" ::: "memory");
    __builtin_amdgcn_s_barrier();
    __builtin_amdgcn_sched_barrier(0);

    f32x4 accx[4];
    {
      const char* xt = xr + c * 128;
      bf16x8 Ax0 = *(const bf16x8*)(xt + (long)((g) ^ (c & 7)) * 16);
      bf16x8 Ax1 = *(const bf16x8*)(xt + (long)((4 + g) ^ (c & 7)) * 16);
#pragma unroll
      for (int gate = 0; gate < 4; ++gate) {
        f32x4 b = (f32x4){bz[gate], bz[gate], bz[gate], bz[gate]};
        accx[gate] = MFMA_BF16(Ax1, Bf[gate][1],
                               MFMA_BF16(Ax0, Bf[gate][0], b, 0, 0, 0), 0, 0, 0);
      }
    }

    int p = 0;
#pragma unroll 2
    for (int t = 0; t < 32; ++t) {
      bf16x8 Ah0 = *(const bf16x8*)((const char*)hl + p * 2048 + l * 16);
      bf16x8 Ah1 = *(const bf16x8*)((const char*)hl + p * 2048 + 1024 + l * 16);

      f32x4 acc[4];
#pragma unroll
      for (int gate = 0; gate < 4; ++gate)
        acc[gate] = MFMA_BF16(Ah1, Bf[gate][3],
                              MFMA_BF16(Ah0, Bf[gate][2], accx[gate], 0, 0, 0),
                              0, 0, 0);

      if (t + 1 < 32) {
        const char* xt = xr + ((t + 1) & 7) * 2048 + c * 128;
        bf16x8 Ax0 = *(const bf16x8*)(xt + (long)((g) ^ (c & 7)) * 16);
        bf16x8 Ax1 = *(const bf16x8*)(xt + (long)((4 + g) ^ (c & 7)) * 16);
#pragma unroll
        for (int gate = 0; gate < 4; ++gate) {
          f32x4 b = (f32x4){bz[gate], bz[gate], bz[gate], bz[gate]};
          accx[gate] = MFMA_BF16(Ax1, Bf[gate][1],
                                 MFMA_BF16(Ax0, Bf[gate][0], b, 0, 0, 0), 0, 0, 0);
        }
      }

      const int wb = (p ^ 1) * 1024;
#pragma unroll
      for (int r = 0; r < 4; ++r) {
        float ei = __expf(-acc[0][r]);
        float ej = __expf(2.f * acc[1][r]);
        float ef = __expf(-(acc[2][r] + 1.f));
        float eo = __expf(-acc[3][r]);
        float p12 = (1.f + ei) * (1.f + ej);
        float r3 = __builtin_amdgcn_rcpf(p12 * (1.f + ef));
        float it = (ej - 1.f) * (1.f + ef) * r3;
        float sf = p12 * r3;
        cs[r] = cs[r] * sf + it;
        float ec = __expf(2.f * cs[r]);
        float r2 = __builtin_amdgcn_rcpf((1.f + eo) * (1.f + ec));
        hl[wb + (hq * 64 + hgp + 4 * g + r) * 8 + hlo] = f2bf_hw((ec - 1.f) * r2);
      }

      if (t + 8 < 32 && w == (t & 3)) K2_STAGE(t + 8);

      if (t + 2 < 32 && w == ((t + 2) & 3))
        asm volatile("s_waitcnt vmcnt(2)" ::: "memory");
      asm volatile("s_waitcnt lgkmcnt(0)" ::: "memory");
      __builtin_amdgcn_s_barrier();
      __builtin_amdgcn_sched_barrier(0);

      if (t >= 1) {
        f32x4 pa = (f32x4){0.f, 0.f, 0.f, 0.f};
        pa = MFMA_BF16(Ah0, Pc[0], pa, 0, 0, 0);
        pa = MFMA_BF16(Ah1, Pc[1], pa, 0, 0, 0);
        if (g == w && c < 8) {
          int tp = dir ? 32 - t : t - 1;
#pragma unroll
          for (int r = 0; r < 4; ++r)
            pl[(4 * g + r) * 256 + tp * 8 + c] = tanh_f(pa[r] + bcv);
        }
      }
      p ^= 1;
    }

    {
      bf16x8 Ph0 = *(const bf16x8*)((const char*)hl + p * 2048 + l * 16);
      bf16x8 Ph1 = *(const bf16x8*)((const char*)hl + p * 2048 + 1024 + l * 16);
      f32x4 pa = (f32x4){0.f, 0.f, 0.f, 0.f};
      pa = MFMA_BF16(Ph0, Pc[0], pa, 0, 0, 0);
      pa = MFMA_BF16(Ph1, Pc[1], pa, 0, 0, 0);
      if (g == w && c < 8) {
        int tp = dir ? 0 : 31;
#pragma unroll
        for (int r = 0; r < 4; ++r)
          pl[(4 * g + r) * 256 + tp * 8 + c] = tanh_f(pa[r] + bcv);
      }
    }

    asm volatile("s_waitcnt lgkmcnt(0)" ::: "memory");
    __builtin_amdgcn_s_barrier();
#pragma unroll
    for (int i = 0; i < 4; ++i) {
      int fi = tid + i * 256;
      int s = fi >> 6, rem = fi & 63;
      int t2 = rem >> 1, a4 = (rem & 1) * 4;
      float4 v = *(const float4*)(pl + s * 256 + t2 * 8 + a4);
      *(float4*)(out + ((long)(dir * 4096 + sq + s) * 32 + t2) * 8 + a4) = v;
    }
  }
}

extern "C" void kernel_launch(void* const* d_in, const int* in_sizes, int n_in,
                              void* d_out, int out_size, void* d_ws, size_t ws_size,
                              hipStream_t stream) {
  const float* obs = (const float*)d_in[0];
  const float* W0  = (const float*)d_in[1];
  const float* b0  = (const float*)d_in[2];
  const float* gam = (const float*)d_in[3];
  const float* bet = (const float*)d_in[4];
  const float* Wfw = (const float*)d_in[5];
  const float* bfw = (const float*)d_in[6];
  const float* Wbw = (const float*)d_in[7];
  const float* bbw = (const float*)d_in[8];
  const float* Wc  = (const float*)d_in[9];
  const float* bc  = (const float*)d_in[10];
  float* out = (float*)d_out;

  unsigned short* wfrag = (unsigned short*)d_ws;       // 64 KB
  unsigned short* wlstm = wfrag + 4096 * 8;            // 128 KB
  unsigned short* xbf   = wlstm + 8192 * 8;            // 16.78 MB

  k0_conv<<<48, 256, 0, stream>>>(W0, Wfw, Wbw, wfrag, wlstm);
  k_dense_ln<<<2048, 256, 0, stream>>>(obs, wfrag, b0, gam, bet, xbf);
  k_lstm<<<512, 256, 0, stream>>>(xbf, wlstm, bfw, bbw, Wc, bc, out);
}

// Round 14
// 113.679 us; speedup vs baseline: 5.3301x; 5.3301x over previous
//
#include <hip/hip_runtime.h>
#include <hip/hip_bf16.h>

typedef __attribute__((ext_vector_type(8))) short bf16x8;
typedef __attribute__((ext_vector_type(4))) float f32x4;

#define MFMA_BF16 __builtin_amdgcn_mfma_f32_16x16x32_bf16

#define GLDS16(gp, lp)                                                        \
  __builtin_amdgcn_global_load_lds(                                           \
      (const __attribute__((address_space(1))) void*)(gp),                    \
      (__attribute__((address_space(3))) void*)(lp), 16, 0, 0)

__device__ __forceinline__ unsigned pk2(float a, float b) {
  __hip_bfloat162 t = __float22bfloat162_rn(make_float2(a, b));
  return *reinterpret_cast<unsigned*>(&t);
}
__device__ __forceinline__ unsigned short f2bf_hw(float f) {
  __hip_bfloat16 h = __float2bfloat16(f);
  return *reinterpret_cast<unsigned short*>(&h);
}
__device__ __forceinline__ float tanh_f(float x) {
  return 1.f - 2.f * __builtin_amdgcn_rcpf(1.f + __expf(2.f * x));
}

// ---------------------------------------------------------------------------
// k0: one-time weight conversion to frag-major bf16 tables in d_ws. (= R11)
// ---------------------------------------------------------------------------
__global__ void k0_conv(const float* __restrict__ W0, const float* __restrict__ Wfw,
                        const float* __restrict__ Wbw, unsigned short* __restrict__ wfrag,
                        unsigned short* __restrict__ wlstm) {
  int gid = blockIdx.x * 256 + threadIdx.x;
  if (gid < 4096) {
    int f = gid >> 6, l = gid & 63;
    int k0 = (f >> 2) * 32 + ((l >> 4) << 3);
    int n = (f & 3) * 16 + (l & 15);
    bf16x8 v;
#pragma unroll
    for (int j = 0; j < 8; ++j) v[j] = (short)f2bf_hw(W0[(k0 + j) * 64 + n]);
    *(bf16x8*)(wfrag + gid * 8) = v;
  } else if (gid < 12288) {
    int g2 = gid - 4096;
    const float* W = (g2 < 4096) ? Wfw : Wbw;
    int f = (g2 & 4095) >> 6, l = g2 & 63;
    int wv = f >> 4, gate = (f >> 2) & 3, kf = f & 3;
    int col = gate * 64 + wv * 16 + (l & 15);
    int kr = kf * 32 + ((l >> 4) << 3);
    bf16x8 v;
#pragma unroll
    for (int j = 0; j < 8; ++j) v[j] = (short)f2bf_hw(W[(kr + j) * 256 + col]);
    *(bf16x8*)(wlstm + g2 * 8) = v;
  }
}

// ---------------------------------------------------------------------------
// K1 REBUILT from R13 counter evidence (latency-bound: VALUBusy 6%, HBM 34%):
// BARRIER-FREE. 2048 blocks x 256 thr; wave owns 16 rows; obs loaded straight
// to registers with a 4-deep prefetch ring (8 dwordx4 in flight per thread);
// B-frags 2-deep from the L2-resident table. LDS only 8 KB (wave-private
// transpose for coalesced stores). Latency hidden by ILP x TLP, no coupling.
// ---------------------------------------------------------------------------
__global__ __launch_bounds__(256, 3) void k_dense_ln(
    const float* __restrict__ obs, const unsigned short* __restrict__ wfrag,
    const float* __restrict__ b0, const float* __restrict__ gam,
    const float* __restrict__ bet, unsigned short* __restrict__ xout) {
  __shared__ unsigned short xs[4096];  // 4 waves x 2 KB (wave-private)
  const int tid = threadIdx.x, w = tid >> 6, l = tid & 63;
  const int g = l >> 4, c = l & 15;
  const long rb = (long)blockIdx.x * 64 + w * 16;

  float b0v[4], gv[4], bv[4];
#pragma unroll
  for (int nt = 0; nt < 4; ++nt) {
    int col = nt * 16 + c;
    b0v[nt] = b0[col]; gv[nt] = gam[col]; bv[nt] = bet[col];
  }

  const float* arow = obs + (rb + c) * 512 + g * 8;  // A row m = c
  const unsigned short* wfl = wfrag + l * 8;

  // 4-deep prefetch ring: slots kf&3
  float4 pa[4], pb[4];
#pragma unroll
  for (int d = 0; d < 4; ++d) {
    pa[d] = *(const float4*)(arow + d * 32);
    pb[d] = *(const float4*)(arow + d * 32 + 4);
  }
  bf16x8 Bc[4];
#pragma unroll
  for (int nt = 0; nt < 4; ++nt) Bc[nt] = *(const bf16x8*)(wfl + nt * 512);

  f32x4 acc[4];
#pragma unroll
  for (int nt = 0; nt < 4; ++nt) acc[nt] = (f32x4){0.f, 0.f, 0.f, 0.f};

#pragma unroll
  for (int kf = 0; kf < 16; ++kf) {
    const int slot = kf & 3;
    union { bf16x8 v; unsigned u[4]; } af;
    af.u[0] = pk2(pa[slot].x, pa[slot].y);
    af.u[1] = pk2(pa[slot].z, pa[slot].w);
    af.u[2] = pk2(pb[slot].x, pb[slot].y);
    af.u[3] = pk2(pb[slot].z, pb[slot].w);
    if (kf + 4 < 16) {  // refill slot 4 ahead
      pa[slot] = *(const float4*)(arow + (kf + 4) * 32);
      pb[slot] = *(const float4*)(arow + (kf + 4) * 32 + 4);
    }
    bf16x8 Bn[4];
    if (kf < 15) {
#pragma unroll
      for (int nt = 0; nt < 4; ++nt)
        Bn[nt] = *(const bf16x8*)(wfl + ((kf + 1) * 4 + nt) * 512);
    }
    acc[0] = MFMA_BF16(af.v, Bc[0], acc[0], 0, 0, 0);
    acc[1] = MFMA_BF16(af.v, Bc[1], acc[1], 0, 0, 0);
    acc[2] = MFMA_BF16(af.v, Bc[2], acc[2], 0, 0, 0);
    acc[3] = MFMA_BF16(af.v, Bc[3], acc[3], 0, 0, 0);
    if (kf < 15) {
#pragma unroll
      for (int nt = 0; nt < 4; ++nt) Bc[nt] = Bn[nt];
    }
  }

  // LN epilogue (D: row = 4*g + r within wave tile, col = nt*16 + c)
  float vv[4][4], s1[4], s2[4];
#pragma unroll
  for (int r = 0; r < 4; ++r) { s1[r] = 0.f; s2[r] = 0.f; }
#pragma unroll
  for (int nt = 0; nt < 4; ++nt)
#pragma unroll
    for (int r = 0; r < 4; ++r) {
      float val = acc[nt][r] + b0v[nt];
      vv[nt][r] = val; s1[r] += val; s2[r] += val * val;
    }
#pragma unroll
  for (int r = 0; r < 4; ++r) {
#pragma unroll
    for (int m = 1; m <= 8; m <<= 1) {
      s1[r] += __shfl_xor(s1[r], m);
      s2[r] += __shfl_xor(s2[r], m);
    }
  }
  // wave-private LDS transpose -> coalesced 16B stores (no barrier needed)
  unsigned short* xw = xs + w * 1024;
#pragma unroll
  for (int r = 0; r < 4; ++r) {
    float mu = s1[r] * 0.015625f;
    float var = s2[r] * 0.015625f - mu * mu;
    float inv = rsqrtf(var + 1e-12f);
    int row = g * 4 + r;
#pragma unroll
    for (int nt = 0; nt < 4; ++nt) {
      float xn = (vv[nt][r] - mu) * inv * gv[nt] + bv[nt];
      xw[(row * 64 + nt * 16 + c) ^ (g << 3)] = f2bf_hw(fmaxf(xn, 0.f));
    }
  }
#pragma unroll
  for (int m2 = 0; m2 < 2; ++m2) {
    int m = m2 * 64 + l;
    int row = m >> 3, u8 = m & 7;
    bf16x8 v = *(const bf16x8*)(xw + ((row * 64 + u8 * 8) ^ ((row >> 2) << 3)));
    *(bf16x8*)(xout + (rb + row) * 64 + u8 * 8) = v;
  }
}

// ---------------------------------------------------------------------------
// K2: EXACTLY R11's validated kernel (512 blocks, 16 seq, 8x2KB ring,
// proj->LDS, rcp-merged gates, accx pipelined).
// ---------------------------------------------------------------------------
__global__ __launch_bounds__(256, 2) void k_lstm(
    const unsigned short* __restrict__ x, const unsigned short* __restrict__ wlstm,
    const float* __restrict__ bfw, const float* __restrict__ bbw,
    const float* __restrict__ Wc, const float* __restrict__ bc,
    float* __restrict__ out) {
  __shared__ __align__(16) char xr[8 * 2048];
  __shared__ unsigned short hl[2 * 1024];
  __shared__ float pl[16 * 32 * 8];
  const int tid = threadIdx.x, w = tid >> 6, l = tid & 63;
  const int g = l >> 4, c = l & 15;
  const int dir = blockIdx.x >> 8;
  const int sq = (blockIdx.x & 255) * 16;
  const float* bias = dir ? bbw : bfw;

  bf16x8 Bf[4][4];
  const unsigned short* wl = wlstm + ((long)dir * 4096 + w * 16 * 64) * 8;
#pragma unroll
  for (int gate = 0; gate < 4; ++gate)
#pragma unroll
    for (int kf = 0; kf < 4; ++kf)
      Bf[gate][kf] = *(const bf16x8*)(wl + ((gate * 4 + kf) * 64 + l) * 8);
  float bz[4];
#pragma unroll
  for (int gate = 0; gate < 4; ++gate) bz[gate] = bias[gate * 64 + w * 16 + c];

  bf16x8 Pc[2];
#pragma unroll
  for (int kf = 0; kf < 2; ++kf)
#pragma unroll
    for (int j = 0; j < 8; ++j) Pc[kf][j] = 0;
  float bcv = 0.f;
  if (c < 8) {
#pragma unroll
    for (int kf = 0; kf < 2; ++kf)
#pragma unroll
      for (int j = 0; j < 8; ++j)
        Pc[kf][j] = (short)f2bf_hw(Wc[(kf * 32 + g * 8 + j) * 8 + c]);
    bcv = bc[c];
  }

  asm volatile("s_waitcnt vmcnt(0)" ::: "memory");

  const int ss = l >> 3, sc = l & 7;
#define K2_STAGE(tt)                                                          \
  {                                                                           \
    int te_ = dir ? 31 - (tt) : (tt);                                         \
    _Pragma("unroll") for (int p_ = 0; p_ < 2; ++p_) {                        \
      int s_ = p_ * 8 + ss;                                                   \
      const char* gp_ = (const char*)x +                                      \
          ((long)(sq + s_) * 32 + te_) * 128 + (long)(sc ^ (s_ & 7)) * 16;    \
      char* lp_ = xr + ((tt) & 7) * 2048 + p_ * 1024;                         \
      GLDS16(gp_, lp_);                                                       \
    }                                                                         \
  }

  K2_STAGE(w);
  K2_STAGE(w + 4);

  for (int i = tid; i < 1024; i += 256) ((unsigned*)hl)[i] = 0u;
  float cs[4] = {0.f, 0.f, 0.f, 0.f};

  if (w < 2) asm volatile("s_waitcnt vmcnt(2)" ::: "memory");
  asm volatile("s_waitcnt lgkmcnt(0)" ::: "memory");
  __builtin_amdgcn_s_barrier();
  __builtin_amdgcn_sched_barrier(0);

  const int hq = w >> 1;
  const int hgp = ((w & 1) * 2 + (c >> 3)) * 16;
  const int hlo = c & 7;

  f32x4 accx[4];
  {
    const char* xt = xr + c * 128;
    bf16x8 Ax0 = *(const bf16x8*)(xt + (long)((g) ^ (c & 7)) * 16);
    bf16x8 Ax1 = *(const bf16x8*)(xt + (long)((4 + g) ^ (c & 7)) * 16);
#pragma unroll
    for (int gate = 0; gate < 4; ++gate) {
      f32x4 b = (f32x4){bz[gate], bz[gate], bz[gate], bz[gate]};
      accx[gate] = MFMA_BF16(Ax1, Bf[gate][1],
                             MFMA_BF16(Ax0, Bf[gate][0], b, 0, 0, 0), 0, 0, 0);
    }
  }

  int p = 0;
#pragma unroll 2
  for (int t = 0; t < 32; ++t) {
    bf16x8 Ah0 = *(const bf16x8*)((const char*)hl + p * 2048 + l * 16);
    bf16x8 Ah1 = *(const bf16x8*)((const char*)hl + p * 2048 + 1024 + l * 16);

    f32x4 acc[4];
#pragma unroll
    for (int gate = 0; gate < 4; ++gate)
      acc[gate] = MFMA_BF16(Ah1, Bf[gate][3],
                            MFMA_BF16(Ah0, Bf[gate][2], accx[gate], 0, 0, 0),
                            0, 0, 0);

    if (t + 1 < 32) {
      const char* xt = xr + ((t + 1) & 7) * 2048 + c * 128;
      bf16x8 Ax0 = *(const bf16x8*)(xt + (long)((g) ^ (c & 7)) * 16);
      bf16x8 Ax1 = *(const bf16x8*)(xt + (long)((4 + g) ^ (c & 7)) * 16);
#pragma unroll
      for (int gate = 0; gate < 4; ++gate) {
        f32x4 b = (f32x4){bz[gate], bz[gate], bz[gate], bz[gate]};
        accx[gate] = MFMA_BF16(Ax1, Bf[gate][1],
                               MFMA_BF16(Ax0, Bf[gate][0], b, 0, 0, 0), 0, 0, 0);
      }
    }

    const int wb = (p ^ 1) * 1024;
#pragma unroll
    for (int r = 0; r < 4; ++r) {
      float ei = __expf(-acc[0][r]);
      float ej = __expf(2.f * acc[1][r]);
      float ef = __expf(-(acc[2][r] + 1.f));
      float eo = __expf(-acc[3][r]);
      float p12 = (1.f + ei) * (1.f + ej);
      float r3 = __builtin_amdgcn_rcpf(p12 * (1.f + ef));
      float it = (ej - 1.f) * (1.f + ef) * r3;
      float sf = p12 * r3;
      cs[r] = cs[r] * sf + it;
      float ec = __expf(2.f * cs[r]);
      float r2 = __builtin_amdgcn_rcpf((1.f + eo) * (1.f + ec));
      hl[wb + (hq * 64 + hgp + 4 * g + r) * 8 + hlo] = f2bf_hw((ec - 1.f) * r2);
    }

    if (t + 8 < 32 && w == (t & 3)) K2_STAGE(t + 8);

    if (t + 2 < 32 && w == ((t + 2) & 3))
      asm volatile("s_waitcnt vmcnt(2)" ::: "memory");
    asm volatile("s_waitcnt lgkmcnt(0)" ::: "memory");
    __builtin_amdgcn_s_barrier();
    __builtin_amdgcn_sched_barrier(0);

    if (t >= 1) {
      f32x4 pa = (f32x4){0.f, 0.f, 0.f, 0.f};
      pa = MFMA_BF16(Ah0, Pc[0], pa, 0, 0, 0);
      pa = MFMA_BF16(Ah1, Pc[1], pa, 0, 0, 0);
      if (g == w && c < 8) {
        int tp = dir ? 32 - t : t - 1;
#pragma unroll
        for (int r = 0; r < 4; ++r)
          pl[(4 * g + r) * 256 + tp * 8 + c] = tanh_f(pa[r] + bcv);
      }
    }
    p ^= 1;
  }

  {
    bf16x8 Ph0 = *(const bf16x8*)((const char*)hl + p * 2048 + l * 16);
    bf16x8 Ph1 = *(const bf16x8*)((const char*)hl + p * 2048 + 1024 + l * 16);
    f32x4 pa = (f32x4){0.f, 0.f, 0.f, 0.f};
    pa = MFMA_BF16(Ph0, Pc[0], pa, 0, 0, 0);
    pa = MFMA_BF16(Ph1, Pc[1], pa, 0, 0, 0);
    if (g == w && c < 8) {
      int tp = dir ? 0 : 31;
#pragma unroll
      for (int r = 0; r < 4; ++r)
        pl[(4 * g + r) * 256 + tp * 8 + c] = tanh_f(pa[r] + bcv);
    }
  }

  asm volatile("s_waitcnt lgkmcnt(0)" ::: "memory");
  __builtin_amdgcn_s_barrier();
#pragma unroll
  for (int i = 0; i < 4; ++i) {
    int fi = tid + i * 256;
    int s = fi >> 6, rem = fi & 63;
    int t2 = rem >> 1, a4 = (rem & 1) * 4;
    float4 v = *(const float4*)(pl + s * 256 + t2 * 8 + a4);
    *(float4*)(out + ((long)(dir * 4096 + sq + s) * 32 + t2) * 8 + a4) = v;
  }
}

extern "C" void kernel_launch(void* const* d_in, const int* in_sizes, int n_in,
                              void* d_out, int out_size, void* d_ws, size_t ws_size,
                              hipStream_t stream) {
  const float* obs = (const float*)d_in[0];
  const float* W0  = (const float*)d_in[1];
  const float* b0  = (const float*)d_in[2];
  const float* gam = (const float*)d_in[3];
  const float* bet = (const float*)d_in[4];
  const float* Wfw = (const float*)d_in[5];
  const float* bfw = (const float*)d_in[6];
  const float* Wbw = (const float*)d_in[7];
  const float* bbw = (const float*)d_in[8];
  const float* Wc  = (const float*)d_in[9];
  const float* bc  = (const float*)d_in[10];
  float* out = (float*)d_out;

  unsigned short* wfrag = (unsigned short*)d_ws;       // 64 KB
  unsigned short* wlstm = wfrag + 4096 * 8;            // 128 KB
  unsigned short* xbf   = wlstm + 8192 * 8;            // 16.78 MB

  k0_conv<<<48, 256, 0, stream>>>(W0, Wfw, Wbw, wfrag, wlstm);
  k_dense_ln<<<2048, 256, 0, stream>>>(obs, wfrag, b0, gam, bet, xbf);
  k_lstm<<<512, 256, 0, stream>>>(xbf, wlstm, bfw, bbw, Wc, bc, out);
}

// Round 15
// 112.319 us; speedup vs baseline: 5.3946x; 1.0121x over previous
//
#include <hip/hip_runtime.h>
#include <hip/hip_bf16.h>

typedef __attribute__((ext_vector_type(8))) short bf16x8;
typedef __attribute__((ext_vector_type(4))) float f32x4;

#define MFMA_BF16 __builtin_amdgcn_mfma_f32_16x16x32_bf16

#define GLDS16(gp, lp)                                                        \
  __builtin_amdgcn_global_load_lds(                                           \
      (const __attribute__((address_space(1))) void*)(gp),                    \
      (__attribute__((address_space(3))) void*)(lp), 16, 0, 0)

__device__ __forceinline__ unsigned pk2(float a, float b) {
  __hip_bfloat162 t = __float22bfloat162_rn(make_float2(a, b));
  return *reinterpret_cast<unsigned*>(&t);
}
__device__ __forceinline__ unsigned short f2bf_hw(float f) {
  __hip_bfloat16 h = __float2bfloat16(f);
  return *reinterpret_cast<unsigned short*>(&h);
}
__device__ __forceinline__ float sigm(float x) {
  return __builtin_amdgcn_rcpf(1.f + __expf(-x));
}

// ---------------------------------------------------------------------------
// k0: one-time weight conversion to frag-major bf16 tables in d_ws.
// ---------------------------------------------------------------------------
__global__ void k0_conv(const float* __restrict__ W0, const float* __restrict__ Wfw,
                        const float* __restrict__ Wbw, unsigned short* __restrict__ wfrag,
                        unsigned short* __restrict__ wlstm) {
  int gid = blockIdx.x * 256 + threadIdx.x;
  if (gid < 4096) {
    int f = gid >> 6, l = gid & 63;
    int k0 = (f >> 2) * 32 + ((l >> 4) << 3);
    int n = (f & 3) * 16 + (l & 15);
    bf16x8 v;
#pragma unroll
    for (int j = 0; j < 8; ++j) v[j] = (short)f2bf_hw(W0[(k0 + j) * 64 + n]);
    *(bf16x8*)(wfrag + gid * 8) = v;
  } else if (gid < 12288) {
    int g2 = gid - 4096;
    const float* W = (g2 < 4096) ? Wfw : Wbw;
    int f = (g2 & 4095) >> 6, l = g2 & 63;
    int wv = f >> 4, gate = (f >> 2) & 3, kf = f & 3;
    int col = gate * 64 + wv * 16 + (l & 15);
    int kr = kf * 32 + ((l >> 4) << 3);
    bf16x8 v;
#pragma unroll
    for (int j = 0; j < 8; ++j) v[j] = (short)f2bf_hw(W[(kr + j) * 256 + col]);
    *(bf16x8*)(wlstm + g2 * 8) = v;
  }
}

// ---------------------------------------------------------------------------
// K1 PERSISTENT: 1024 blocks x 256 thr, 2 contiguous 64-row tiles per block.
// 16-chunk continuous ring (3 x 16 KB, R8 skeleton) spanning both tiles: no
// drain/re-ramp at the tile boundary. LN at chunks 7/15 reduces to REGISTERS
// (hv), keeping the in-loop vmcnt FIFO store-free (VW exact). Transpose +
// stores for both tiles after the loop via ring slot 1 (free after barrier 15).
// ---------------------------------------------------------------------------
__global__ __launch_bounds__(256, 3) void k_dense_ln(
    const float* __restrict__ obs, const unsigned short* __restrict__ wfrag,
    const float* __restrict__ b0, const float* __restrict__ gam,
    const float* __restrict__ bet, unsigned short* __restrict__ xout) {
  __shared__ __align__(16) char lds[49152];  // 3 x 16 KB ring
  const int tid = threadIdx.x, w = tid >> 6, l = tid & 63;
  const int g = l >> 4, c = l & 15;

  float b0v[4], gv[4], bv[4];
#pragma unroll
  for (int nt = 0; nt < 4; ++nt) {
    int col = nt * 16 + c;
    b0v[nt] = b0[col]; gv[nt] = gam[col]; bv[nt] = bet[col];
  }
  const unsigned short* wfl = wfrag + l * 8;
  const char* gB = (const char*)obs + (long)blockIdx.x * 262144;  // 2 tiles
  const int rlo = w * 4 + g;

  asm volatile("s_waitcnt vmcnt(0)" ::: "memory");

  // chunk cc (0..15): tile = cc>>3 (tile stride 128 KB), q-in-tile = cc&7
#define K1_STAGE(cc)                                                          \
  {                                                                           \
    _Pragma("unroll") for (int i = 0; i < 4; ++i) {                           \
      int row_ = i * 16 + rlo;                                                \
      const char* gp_ = gB + ((cc) >> 3) * 131072 + (long)row_ * 2048 +       \
                        ((cc) & 7) * 256 + (long)((c ^ rlo) * 16);            \
      char* lp_ = lds + ((cc) % 3) * 16384 + (i * 4096 + (w * 64 + l) * 16);  \
      GLDS16(gp_, lp_);                                                       \
    }                                                                         \
  }

  K1_STAGE(0);
  K1_STAGE(1);
  K1_STAGE(2);

  f32x4 acc[4];
#pragma unroll
  for (int nt = 0; nt < 4; ++nt) acc[nt] = (f32x4){0.f, 0.f, 0.f, 0.f};
  unsigned short hv[2][16];  // per-tile LN'd bf16 results (rows x nt)

#pragma unroll
  for (int qq = 0; qq < 16; ++qq) {
    // outstanding-after-stage(qq), store-free FIFO (derived exactly):
    constexpr int VW[16] = {8, 16, 24, 24, 24, 24, 24, 24,
                            24, 24, 24, 24, 24, 24, 20, 16};
    asm volatile("s_waitcnt vmcnt(%0)" :: "i"(VW[qq]) : "memory");
    __builtin_amdgcn_s_barrier();
    __builtin_amdgcn_sched_barrier(0);

    const char* rowb = lds + (qq % 3) * 16384 + (w * 16 + c) * 256;
#pragma unroll
    for (int kf = 0; kf < 2; ++kf) {
      int fb = ((qq & 7) * 2 + kf) * 4;
      bf16x8 B0 = *(const bf16x8*)(wfl + (fb + 0) * 512);
      bf16x8 B1 = *(const bf16x8*)(wfl + (fb + 1) * 512);
      bf16x8 B2 = *(const bf16x8*)(wfl + (fb + 2) * 512);
      bf16x8 B3 = *(const bf16x8*)(wfl + (fb + 3) * 512);
      int u0 = kf * 8 + g * 2;
      float4 f0 = *(const float4*)(rowb + ((u0 + 0) ^ c) * 16);
      float4 f1 = *(const float4*)(rowb + ((u0 + 1) ^ c) * 16);
      union { bf16x8 v; unsigned u[4]; } af;
      af.u[0] = pk2(f0.x, f0.y); af.u[1] = pk2(f0.z, f0.w);
      af.u[2] = pk2(f1.x, f1.y); af.u[3] = pk2(f1.z, f1.w);
      acc[0] = MFMA_BF16(af.v, B0, acc[0], 0, 0, 0);
      acc[1] = MFMA_BF16(af.v, B1, acc[1], 0, 0, 0);
      acc[2] = MFMA_BF16(af.v, B2, acc[2], 0, 0, 0);
      acc[3] = MFMA_BF16(af.v, B3, acc[3], 0, 0, 0);
    }
    if (qq < 13) {  // last stage issued at qq=12 (chunk 15)
      __builtin_amdgcn_s_barrier();   // all waves done reading slot qq%3
      __builtin_amdgcn_sched_barrier(0);
      K1_STAGE(qq + 3);
    }
    if ((qq & 7) == 7) {  // tile (qq>>3) K-complete: LN to registers, no mem
      const int tile = qq >> 3;
      float vv[4][4], s1[4], s2[4];
#pragma unroll
      for (int r = 0; r < 4; ++r) { s1[r] = 0.f; s2[r] = 0.f; }
#pragma unroll
      for (int nt = 0; nt < 4; ++nt)
#pragma unroll
        for (int r = 0; r < 4; ++r) {
          float val = acc[nt][r] + b0v[nt];
          vv[nt][r] = val; s1[r] += val; s2[r] += val * val;
        }
#pragma unroll
      for (int r = 0; r < 4; ++r) {
#pragma unroll
        for (int m = 1; m <= 8; m <<= 1) {
          s1[r] += __shfl_xor(s1[r], m);
          s2[r] += __shfl_xor(s2[r], m);
        }
      }
#pragma unroll
      for (int r = 0; r < 4; ++r) {
        float mu = s1[r] * 0.015625f;
        float var = s2[r] * 0.015625f - mu * mu;
        float inv = rsqrtf(var + 1e-12f);
#pragma unroll
        for (int nt = 0; nt < 4; ++nt) {
          float xn = (vv[nt][r] - mu) * inv * gv[nt] + bv[nt];
          hv[tile][r * 4 + nt] = f2bf_hw(fmaxf(xn, 0.f));
        }
      }
#pragma unroll
      for (int nt = 0; nt < 4; ++nt) acc[nt] = (f32x4){0.f, 0.f, 0.f, 0.f};
    }
  }

  // epilogue: both tiles transpose via ring slot 1 (chunk 13's region — all
  // waves passed barrier(15), so it is free). Wave-private 2 KB each.
  unsigned short* xw = (unsigned short*)(lds + 16384) + w * 1024;
#pragma unroll
  for (int tile = 0; tile < 2; ++tile) {
    const long rbt = ((long)blockIdx.x * 2 + tile) * 64 + w * 16;
#pragma unroll
    for (int r = 0; r < 4; ++r) {
      int row = g * 4 + r;
#pragma unroll
      for (int nt = 0; nt < 4; ++nt)
        xw[(row * 64 + nt * 16 + c) ^ (g << 3)] = hv[tile][r * 4 + nt];
    }
#pragma unroll
    for (int m2 = 0; m2 < 2; ++m2) {
      int m = m2 * 64 + l;
      int row = m >> 3, u8 = m & 7;
      bf16x8 v = *(const bf16x8*)(xw + ((row * 64 + u8 * 8) ^ ((row >> 2) << 3)));
      *(bf16x8*)(xout + (rbt + row) * 64 + u8 * 8) = v;
    }
  }
}

// ---------------------------------------------------------------------------
// K2: byte-identical to the best-measured build (102.3 us): 512 blocks,
// 64-KB x-tile staged wave-owned in consumption order, counted owner vmcnt
// (slot t+2), accx pipelined, rcp-merged gates, w==0 projection.
// ---------------------------------------------------------------------------
__global__ __launch_bounds__(256, 2) void k_lstm(
    const unsigned short* __restrict__ x, const unsigned short* __restrict__ wlstm,
    const float* __restrict__ bfw, const float* __restrict__ bbw,
    const float* __restrict__ Wc, const float* __restrict__ bc,
    float* __restrict__ out) {
  __shared__ __align__(16) char xl[65536];
  __shared__ unsigned short hl[2 * 1024];
  const int tid = threadIdx.x, w = tid >> 6, l = tid & 63;
  const int g = l >> 4, c = l & 15;
  const int dir = blockIdx.x >> 8;
  const int sq = (blockIdx.x & 255) * 16;
  const float* bias = dir ? bbw : bfw;

  bf16x8 Bf[4][4];
  const unsigned short* wl = wlstm + ((long)dir * 4096 + w * 16 * 64) * 8;
#pragma unroll
  for (int gate = 0; gate < 4; ++gate)
#pragma unroll
    for (int kf = 0; kf < 4; ++kf)
      Bf[gate][kf] = *(const bf16x8*)(wl + ((gate * 4 + kf) * 64 + l) * 8);
  float bz[4];
#pragma unroll
  for (int gate = 0; gate < 4; ++gate) bz[gate] = bias[gate * 64 + w * 16 + c];

  bf16x8 Pc[2];
#pragma unroll
  for (int kf = 0; kf < 2; ++kf)
#pragma unroll
    for (int j = 0; j < 8; ++j) Pc[kf][j] = 0;
  float bcv = 0.f;
  if (w == 0 && c < 8) {
#pragma unroll
    for (int kf = 0; kf < 2; ++kf)
#pragma unroll
      for (int j = 0; j < 8; ++j)
        Pc[kf][j] = (short)f2bf_hw(Wc[(kf * 32 + g * 8 + j) * 8 + c]);
    bcv = bc[c];
  }

  asm volatile("s_waitcnt vmcnt(0)" ::: "memory");

  const int ss = l >> 3, sc = l & 7;
#pragma unroll
  for (int j = 0; j < 8; ++j) {
    int tt = w * 8 + j;
    int te = dir ? 31 - tt : tt;
#pragma unroll
    for (int p = 0; p < 2; ++p) {
      int s = p * 8 + ss;
      const char* gp = (const char*)x +
          ((long)(sq + s) * 32 + te) * 128 + (long)(sc ^ (s & 7)) * 16;
      char* lp = xl + tt * 2048 + p * 1024;
      GLDS16(gp, lp);
    }
  }

  for (int i = tid; i < 1024; i += 256) ((unsigned*)hl)[i] = 0u;
  float cs[4] = {0.f, 0.f, 0.f, 0.f};

  if (w == 0) asm volatile("s_waitcnt vmcnt(12)" ::: "memory");
  asm volatile("s_waitcnt lgkmcnt(0)" ::: "memory");
  __builtin_amdgcn_s_barrier();
  __builtin_amdgcn_sched_barrier(0);

  const int hq = w >> 1;
  const int hgp = ((w & 1) * 2 + (c >> 3)) * 16;
  const int hlo = c & 7;

  f32x4 accx[4];
  {
    const char* xt = xl + 0 * 2048 + c * 128;
    bf16x8 Ax0 = *(const bf16x8*)(xt + (long)((g) ^ (c & 7)) * 16);
    bf16x8 Ax1 = *(const bf16x8*)(xt + (long)((4 + g) ^ (c & 7)) * 16);
#pragma unroll
    for (int gate = 0; gate < 4; ++gate) {
      f32x4 b = (f32x4){bz[gate], bz[gate], bz[gate], bz[gate]};
      accx[gate] = MFMA_BF16(Ax1, Bf[gate][1],
                             MFMA_BF16(Ax0, Bf[gate][0], b, 0, 0, 0), 0, 0, 0);
    }
  }

  int p = 0;
#pragma unroll
  for (int t = 0; t < 32; ++t) {
    bf16x8 Ah0 = *(const bf16x8*)((const char*)hl + p * 2048 + l * 16);
    bf16x8 Ah1 = *(const bf16x8*)((const char*)hl + p * 2048 + 1024 + l * 16);

    f32x4 acc[4];
#pragma unroll
    for (int gate = 0; gate < 4; ++gate)
      acc[gate] = MFMA_BF16(Ah1, Bf[gate][3],
                            MFMA_BF16(Ah0, Bf[gate][2], accx[gate], 0, 0, 0),
                            0, 0, 0);

    if (t + 1 < 32) {
      const char* xt = xl + (t + 1) * 2048 + c * 128;
      bf16x8 Ax0 = *(const bf16x8*)(xt + (long)((g) ^ (c & 7)) * 16);
      bf16x8 Ax1 = *(const bf16x8*)(xt + (long)((4 + g) ^ (c & 7)) * 16);
#pragma unroll
      for (int gate = 0; gate < 4; ++gate) {
        f32x4 b = (f32x4){bz[gate], bz[gate], bz[gate], bz[gate]};
        accx[gate] = MFMA_BF16(Ax1, Bf[gate][1],
                               MFMA_BF16(Ax0, Bf[gate][0], b, 0, 0, 0), 0, 0, 0);
      }
    }

    const int wb = (p ^ 1) * 1024;
#pragma unroll
    for (int r = 0; r < 4; ++r) {
      float ei = __expf(-acc[0][r]);
      float ej = __expf(2.f * acc[1][r]);
      float ef = __expf(-(acc[2][r] + 1.f));
      float eo = __expf(-acc[3][r]);
      float p12 = (1.f + ei) * (1.f + ej);
      float r3 = __builtin_amdgcn_rcpf(p12 * (1.f + ef));
      float it = (ej - 1.f) * (1.f + ef) * r3;
      float sf = p12 * r3;
      cs[r] = cs[r] * sf + it;
      float ec = __expf(2.f * cs[r]);
      float r2 = __builtin_amdgcn_rcpf((1.f + eo) * (1.f + ec));
      hl[wb + (hq * 64 + hgp + 4 * g + r) * 8 + hlo] = f2bf_hw((ec - 1.f) * r2);
    }

    if (t + 2 < 32) {
      if (w == ((t + 2) >> 3))
        asm volatile("s_waitcnt vmcnt(%0)" :: "i"(14 - 2 * ((t + 2) & 7)) : "memory");
    }
    asm volatile("s_waitcnt lgkmcnt(0)" ::: "memory");
    __builtin_amdgcn_s_barrier();
    __builtin_amdgcn_sched_barrier(0);

    if (w == 0 && t >= 1) {
      f32x4 pa = (f32x4){0.f, 0.f, 0.f, 0.f};
      pa = MFMA_BF16(Ah0, Pc[0], pa, 0, 0, 0);
      pa = MFMA_BF16(Ah1, Pc[1], pa, 0, 0, 0);
      if (c < 8) {
        int tp = dir ? 32 - t : t - 1;
#pragma unroll
        for (int r = 0; r < 4; ++r) {
          long orow = (long)dir * 4096 + sq + 4 * g + r;
          out[(orow * 32 + tp) * 8 + c] = tanhf(pa[r] + bcv);
        }
      }
    }
    p ^= 1;
  }

  if (w == 0) {
    bf16x8 Ph0 = *(const bf16x8*)((const char*)hl + p * 2048 + l * 16);
    bf16x8 Ph1 = *(const bf16x8*)((const char*)hl + p * 2048 + 1024 + l * 16);
    f32x4 pa = (f32x4){0.f, 0.f, 0.f, 0.f};
    pa = MFMA_BF16(Ph0, Pc[0], pa, 0, 0, 0);
    pa = MFMA_BF16(Ph1, Pc[1], pa, 0, 0, 0);
    if (c < 8) {
      int tp = dir ? 0 : 31;
#pragma unroll
      for (int r = 0; r < 4; ++r) {
        long orow = (long)dir * 4096 + sq + 4 * g + r;
        out[(orow * 32 + tp) * 8 + c] = tanhf(pa[r] + bcv);
      }
    }
  }
}

extern "C" void kernel_launch(void* const* d_in, const int* in_sizes, int n_in,
                              void* d_out, int out_size, void* d_ws, size_t ws_size,
                              hipStream_t stream) {
  const float* obs = (const float*)d_in[0];
  const float* W0  = (const float*)d_in[1];
  const float* b0  = (const float*)d_in[2];
  const float* gam = (const float*)d_in[3];
  const float* bet = (const float*)d_in[4];
  const float* Wfw = (const float*)d_in[5];
  const float* bfw = (const float*)d_in[6];
  const float* Wbw = (const float*)d_in[7];
  const float* bbw = (const float*)d_in[8];
  const float* Wc  = (const float*)d_in[9];
  const float* bc  = (const float*)d_in[10];
  float* out = (float*)d_out;

  unsigned short* wfrag = (unsigned short*)d_ws;       // 64 KB
  unsigned short* wlstm = wfrag + 4096 * 8;            // 128 KB
  unsigned short* xbf   = wlstm + 8192 * 8;            // 16.78 MB

  k0_conv<<<48, 256, 0, stream>>>(W0, Wfw, Wbw, wfrag, wlstm);
  k_dense_ln<<<1024, 256, 0, stream>>>(obs, wfrag, b0, gam, bet, xbf);
  k_lstm<<<512, 256, 0, stream>>>(xbf, wlstm, bfw, bbw, Wc, bc, out);
}

// Round 16
// 98.583 us; speedup vs baseline: 6.1463x; 1.1393x over previous
//
#include <hip/hip_runtime.h>
#include <hip/hip_bf16.h>

typedef __attribute__((ext_vector_type(8))) short bf16x8;
typedef __attribute__((ext_vector_type(4))) float f32x4;

#define MFMA_BF16 __builtin_amdgcn_mfma_f32_16x16x32_bf16

#define GLDS16(gp, lp)                                                        \
  __builtin_amdgcn_global_load_lds(                                           \
      (const __attribute__((address_space(1))) void*)(gp),                    \
      (__attribute__((address_space(3))) void*)(lp), 16, 0, 0)

__device__ __forceinline__ unsigned pk2(float a, float b) {
  __hip_bfloat162 t = __float22bfloat162_rn(make_float2(a, b));
  return *reinterpret_cast<unsigned*>(&t);
}
__device__ __forceinline__ unsigned short f2bf_hw(float f) {
  __hip_bfloat16 h = __float2bfloat16(f);
  return *reinterpret_cast<unsigned short*>(&h);
}
__device__ __forceinline__ float tanh_f(float x) {
  return 1.f - 2.f * __builtin_amdgcn_rcpf(1.f + __expf(2.f * x));
}

// ---------------------------------------------------------------------------
// k0: one-time weight conversion to frag-major bf16 tables in d_ws. (= R8)
// ---------------------------------------------------------------------------
__global__ void k0_conv(const float* __restrict__ W0, const float* __restrict__ Wfw,
                        const float* __restrict__ Wbw, unsigned short* __restrict__ wfrag,
                        unsigned short* __restrict__ wlstm) {
  int gid = blockIdx.x * 256 + threadIdx.x;
  if (gid < 4096) {
    int f = gid >> 6, l = gid & 63;
    int k0 = (f >> 2) * 32 + ((l >> 4) << 3);
    int n = (f & 3) * 16 + (l & 15);
    bf16x8 v;
#pragma unroll
    for (int j = 0; j < 8; ++j) v[j] = (short)f2bf_hw(W0[(k0 + j) * 64 + n]);
    *(bf16x8*)(wfrag + gid * 8) = v;
  } else if (gid < 12288) {
    int g2 = gid - 4096;
    const float* W = (g2 < 4096) ? Wfw : Wbw;
    int f = (g2 & 4095) >> 6, l = g2 & 63;
    int wv = f >> 4, gate = (f >> 2) & 3, kf = f & 3;
    int col = gate * 64 + wv * 16 + (l & 15);
    int kr = kf * 32 + ((l >> 4) << 3);
    bf16x8 v;
#pragma unroll
    for (int j = 0; j < 8; ++j) v[j] = (short)f2bf_hw(W[(kr + j) * 256 + col]);
    *(bf16x8*)(wlstm + g2 * 8) = v;
  }
}

// ---------------------------------------------------------------------------
// K1: EXACTLY the R8 kernel (best measured: part of the 102.3 us build).
// ---------------------------------------------------------------------------
__global__ __launch_bounds__(256, 3) void k_dense_ln(
    const float* __restrict__ obs, const unsigned short* __restrict__ wfrag,
    const float* __restrict__ b0, const float* __restrict__ gam,
    const float* __restrict__ bet, unsigned short* __restrict__ xout) {
  __shared__ __align__(16) char lds[49152];  // 3 x 16 KB
  const int tid = threadIdx.x, w = tid >> 6, l = tid & 63;
  const int g = l >> 4, c = l & 15;
  const long blk64 = (long)blockIdx.x * 64;
  const long rb = blk64 + w * 16;

  float b0v[4], gv[4], bv[4];
#pragma unroll
  for (int nt = 0; nt < 4; ++nt) {
    int col = nt * 16 + c;
    b0v[nt] = b0[col]; gv[nt] = gam[col]; bv[nt] = bet[col];
  }
  const unsigned short* wfl = wfrag + l * 8;
  const char* gB = (const char*)obs + blk64 * 2048;

  const int rlo = w * 4 + g;
  asm volatile("s_waitcnt vmcnt(0)" ::: "memory");

#define K1_STAGE(q)                                                           \
  {                                                                           \
    _Pragma("unroll") for (int i = 0; i < 4; ++i) {                           \
      int row_ = i * 16 + rlo;                                                \
      const char* gp_ = gB + (long)row_ * 2048 + (q) * 256 +                  \
                        (long)((c ^ rlo) * 16);                               \
      char* lp_ = lds + ((q) % 3) * 16384 + (i * 4096 + (w * 64 + l) * 16);   \
      GLDS16(gp_, lp_);                                                       \
    }                                                                         \
  }

  K1_STAGE(0);
  K1_STAGE(1);
  K1_STAGE(2);

  f32x4 acc[4];
#pragma unroll
  for (int nt = 0; nt < 4; ++nt) acc[nt] = (f32x4){0.f, 0.f, 0.f, 0.f};

#pragma unroll
  for (int q = 0; q < 8; ++q) {
    constexpr int VW[8] = {8, 16, 24, 24, 24, 24, 20, 16};
    asm volatile("s_waitcnt vmcnt(%0)" :: "i"(VW[q]) : "memory");
    __builtin_amdgcn_s_barrier();
    __builtin_amdgcn_sched_barrier(0);

    const char* rowb = lds + (q % 3) * 16384 + (w * 16 + c) * 256;
#pragma unroll
    for (int kf = 0; kf < 2; ++kf) {
      int fb = (q * 2 + kf) * 4;
      bf16x8 B0 = *(const bf16x8*)(wfl + (fb + 0) * 512);
      bf16x8 B1 = *(const bf16x8*)(wfl + (fb + 1) * 512);
      bf16x8 B2 = *(const bf16x8*)(wfl + (fb + 2) * 512);
      bf16x8 B3 = *(const bf16x8*)(wfl + (fb + 3) * 512);
      int u0 = kf * 8 + g * 2;
      float4 f0 = *(const float4*)(rowb + ((u0 + 0) ^ c) * 16);
      float4 f1 = *(const float4*)(rowb + ((u0 + 1) ^ c) * 16);
      union { bf16x8 v; unsigned u[4]; } af;
      af.u[0] = pk2(f0.x, f0.y); af.u[1] = pk2(f0.z, f0.w);
      af.u[2] = pk2(f1.x, f1.y); af.u[3] = pk2(f1.z, f1.w);
      acc[0] = MFMA_BF16(af.v, B0, acc[0], 0, 0, 0);
      acc[1] = MFMA_BF16(af.v, B1, acc[1], 0, 0, 0);
      acc[2] = MFMA_BF16(af.v, B2, acc[2], 0, 0, 0);
      acc[3] = MFMA_BF16(af.v, B3, acc[3], 0, 0, 0);
    }
    if (q < 5) {
      __builtin_amdgcn_s_barrier();
      __builtin_amdgcn_sched_barrier(0);
      K1_STAGE(q + 3);
    }
  }

  float vv[4][4], s1[4], s2[4];
#pragma unroll
  for (int r = 0; r < 4; ++r) { s1[r] = 0.f; s2[r] = 0.f; }
#pragma unroll
  for (int nt = 0; nt < 4; ++nt)
#pragma unroll
    for (int r = 0; r < 4; ++r) {
      float val = acc[nt][r] + b0v[nt];
      vv[nt][r] = val; s1[r] += val; s2[r] += val * val;
    }
#pragma unroll
  for (int r = 0; r < 4; ++r) {
#pragma unroll
    for (int m = 1; m <= 8; m <<= 1) {
      s1[r] += __shfl_xor(s1[r], m);
      s2[r] += __shfl_xor(s2[r], m);
    }
  }
  unsigned short* xw = (unsigned short*)lds + w * 1024;
#pragma unroll
  for (int r = 0; r < 4; ++r) {
    float mu = s1[r] * 0.015625f;
    float var = s2[r] * 0.015625f - mu * mu;
    float inv = rsqrtf(var + 1e-12f);
    int row = g * 4 + r;
#pragma unroll
    for (int nt = 0; nt < 4; ++nt) {
      float xn = (vv[nt][r] - mu) * inv * gv[nt] + bv[nt];
      xw[(row * 64 + nt * 16 + c) ^ (g << 3)] = f2bf_hw(fmaxf(xn, 0.f));
    }
  }
#pragma unroll
  for (int m2 = 0; m2 < 2; ++m2) {
    int m = m2 * 64 + l;
    int row = m >> 3, u8 = m & 7;
    bf16x8 v = *(const bf16x8*)(xw + ((row * 64 + u8 * 8) ^ ((row >> 2) << 3)));
    *(bf16x8*)(xout + (rb + row) * 64 + u8 * 8) = v;
  }
}

// ---------------------------------------------------------------------------
// K2: R8 skeleton (512 blocks, 64-KB upfront wave-owned staging, counted
// owner vmcnt, accx pipelined, rcp-merged gates) with the projection moved
// OUT of the serial loop: h(t) is also written into xl slot t (slot t's x
// was last read at step t-1 -> free), and each wave projects its 8 timesteps
// in a parallel epilogue with fast tanh_f. No stores in the loop's FIFO.
// ---------------------------------------------------------------------------
__global__ __launch_bounds__(256, 2) void k_lstm(
    const unsigned short* __restrict__ x, const unsigned short* __restrict__ wlstm,
    const float* __restrict__ bfw, const float* __restrict__ bbw,
    const float* __restrict__ Wc, const float* __restrict__ bc,
    float* __restrict__ out) {
  __shared__ __align__(16) char xl[65536];   // 32 slots x 2KB: x(t), then h(t)
  __shared__ unsigned short hl[2 * 1024];
  const int tid = threadIdx.x, w = tid >> 6, l = tid & 63;
  const int g = l >> 4, c = l & 15;
  const int dir = blockIdx.x >> 8;
  const int sq = (blockIdx.x & 255) * 16;
  const float* bias = dir ? bbw : bfw;

  bf16x8 Bf[4][4];
  const unsigned short* wl = wlstm + ((long)dir * 4096 + w * 16 * 64) * 8;
#pragma unroll
  for (int gate = 0; gate < 4; ++gate)
#pragma unroll
    for (int kf = 0; kf < 4; ++kf)
      Bf[gate][kf] = *(const bf16x8*)(wl + ((gate * 4 + kf) * 64 + l) * 8);
  float bz[4];
#pragma unroll
  for (int gate = 0; gate < 4; ++gate) bz[gate] = bias[gate * 64 + w * 16 + c];

  // projection weights: ALL waves (each wave projects 8 timesteps at the end)
  bf16x8 Pc[2];
#pragma unroll
  for (int kf = 0; kf < 2; ++kf)
#pragma unroll
    for (int j = 0; j < 8; ++j) Pc[kf][j] = 0;
  float bcv = 0.f;
  if (c < 8) {
#pragma unroll
    for (int kf = 0; kf < 2; ++kf)
#pragma unroll
      for (int j = 0; j < 8; ++j)
        Pc[kf][j] = (short)f2bf_hw(Wc[(kf * 32 + g * 8 + j) * 8 + c]);
    bcv = bc[c];
  }

  asm volatile("s_waitcnt vmcnt(0)" ::: "memory");

  // stage all 32 slots (wave w: slots w*8..w*8+7, consumption order)
  const int ss = l >> 3, sc = l & 7;
#pragma unroll
  for (int j = 0; j < 8; ++j) {
    int tt = w * 8 + j;
    int te = dir ? 31 - tt : tt;
#pragma unroll
    for (int p = 0; p < 2; ++p) {
      int s = p * 8 + ss;
      const char* gp = (const char*)x +
          ((long)(sq + s) * 32 + te) * 128 + (long)(sc ^ (s & 7)) * 16;
      char* lp = xl + tt * 2048 + p * 1024;
      GLDS16(gp, lp);
    }
  }

  for (int i = tid; i < 1024; i += 256) ((unsigned*)hl)[i] = 0u;
  float cs[4] = {0.f, 0.f, 0.f, 0.f};

  // prologue: slots 0 AND 1 resident (accx(0) now, accx(1) in step 0)
  if (w == 0) asm volatile("s_waitcnt vmcnt(12)" ::: "memory");
  asm volatile("s_waitcnt lgkmcnt(0)" ::: "memory");
  __builtin_amdgcn_s_barrier();
  __builtin_amdgcn_sched_barrier(0);

  const int hq = w >> 1;
  const int hgp = ((w & 1) * 2 + (c >> 3)) * 16;
  const int hlo = c & 7;

  // accx(0) from slot 0
  f32x4 accx[4];
  {
    const char* xt = xl + 0 * 2048 + c * 128;
    bf16x8 Ax0 = *(const bf16x8*)(xt + (long)((g) ^ (c & 7)) * 16);
    bf16x8 Ax1 = *(const bf16x8*)(xt + (long)((4 + g) ^ (c & 7)) * 16);
#pragma unroll
    for (int gate = 0; gate < 4; ++gate) {
      f32x4 b = (f32x4){bz[gate], bz[gate], bz[gate], bz[gate]};
      accx[gate] = MFMA_BF16(Ax1, Bf[gate][1],
                             MFMA_BF16(Ax0, Bf[gate][0], b, 0, 0, 0), 0, 0, 0);
    }
  }
  // close the t=0 hazard window: all waves done reading slot 0 before any
  // wave writes h(0) into it during step 0's elementwise
  asm volatile("s_waitcnt lgkmcnt(0)" ::: "memory");
  __builtin_amdgcn_s_barrier();
  __builtin_amdgcn_sched_barrier(0);

  int p = 0;
#pragma unroll
  for (int t = 0; t < 32; ++t) {
    bf16x8 Ah0 = *(const bf16x8*)((const char*)hl + p * 2048 + l * 16);
    bf16x8 Ah1 = *(const bf16x8*)((const char*)hl + p * 2048 + 1024 + l * 16);

    f32x4 acc[4];
#pragma unroll
    for (int gate = 0; gate < 4; ++gate)
      acc[gate] = MFMA_BF16(Ah1, Bf[gate][3],
                            MFMA_BF16(Ah0, Bf[gate][2], accx[gate], 0, 0, 0),
                            0, 0, 0);

    // accx(t+1) from slot t+1 (still holds x(t+1); h(t+1) written only at
    // step t+1, after this step's barrier)
    if (t + 1 < 32) {
      const char* xt = xl + (t + 1) * 2048 + c * 128;
      bf16x8 Ax0 = *(const bf16x8*)(xt + (long)((g) ^ (c & 7)) * 16);
      bf16x8 Ax1 = *(const bf16x8*)(xt + (long)((4 + g) ^ (c & 7)) * 16);
#pragma unroll
      for (int gate = 0; gate < 4; ++gate) {
        f32x4 b = (f32x4){bz[gate], bz[gate], bz[gate], bz[gate]};
        accx[gate] = MFMA_BF16(Ax1, Bf[gate][1],
                               MFMA_BF16(Ax0, Bf[gate][0], b, 0, 0, 0), 0, 0, 0);
      }
    }

    // rcp-merged gates; h(t) -> hl (recurrence) AND xl slot t (history)
    const int wb = (p ^ 1) * 1024;
    unsigned short* xh = (unsigned short*)xl + t * 1024;
#pragma unroll
    for (int r = 0; r < 4; ++r) {
      float ei = __expf(-acc[0][r]);
      float ej = __expf(2.f * acc[1][r]);
      float ef = __expf(-(acc[2][r] + 1.f));
      float eo = __expf(-acc[3][r]);
      float p12 = (1.f + ei) * (1.f + ej);
      float r3 = __builtin_amdgcn_rcpf(p12 * (1.f + ef));
      float it = (ej - 1.f) * (1.f + ef) * r3;
      float sf = p12 * r3;
      cs[r] = cs[r] * sf + it;
      float ec = __expf(2.f * cs[r]);
      float r2 = __builtin_amdgcn_rcpf((1.f + eo) * (1.f + ec));
      unsigned short hb = f2bf_hw((ec - 1.f) * r2);
      int off = (hq * 64 + hgp + 4 * g + r) * 8 + hlo;
      hl[wb + off] = hb;
      xh[off] = hb;
    }

    // owner guarantees slot t+2 resident before next step (reads Ax(t+2))
    if (t + 2 < 32) {
      if (w == ((t + 2) >> 3))
        asm volatile("s_waitcnt vmcnt(%0)" :: "i"(14 - 2 * ((t + 2) & 7)) : "memory");
    }
    asm volatile("s_waitcnt lgkmcnt(0)" ::: "memory");
    __builtin_amdgcn_s_barrier();
    __builtin_amdgcn_sched_barrier(0);
    p ^= 1;
  }

  // parallel projection epilogue: wave w projects timesteps w*8..w*8+7
#pragma unroll
  for (int j = 0; j < 8; ++j) {
    int t = w * 8 + j;
    const char* hb = xl + t * 2048;
    bf16x8 Ph0 = *(const bf16x8*)(hb + l * 16);
    bf16x8 Ph1 = *(const bf16x8*)(hb + 1024 + l * 16);
    f32x4 pa = (f32x4){0.f, 0.f, 0.f, 0.f};
    pa = MFMA_BF16(Ph0, Pc[0], pa, 0, 0, 0);
    pa = MFMA_BF16(Ph1, Pc[1], pa, 0, 0, 0);
    if (c < 8) {
      int tp = dir ? 31 - t : t;  // h(t) belongs to time te = tp
#pragma unroll
      for (int r = 0; r < 4; ++r) {
        long orow = (long)dir * 4096 + sq + 4 * g + r;
        out[(orow * 32 + tp) * 8 + c] = tanh_f(pa[r] + bcv);
      }
    }
  }
}

extern "C" void kernel_launch(void* const* d_in, const int* in_sizes, int n_in,
                              void* d_out, int out_size, void* d_ws, size_t ws_size,
                              hipStream_t stream) {
  const float* obs = (const float*)d_in[0];
  const float* W0  = (const float*)d_in[1];
  const float* b0  = (const float*)d_in[2];
  const float* gam = (const float*)d_in[3];
  const float* bet = (const float*)d_in[4];
  const float* Wfw = (const float*)d_in[5];
  const float* bfw = (const float*)d_in[6];
  const float* Wbw = (const float*)d_in[7];
  const float* bbw = (const float*)d_in[8];
  const float* Wc  = (const float*)d_in[9];
  const float* bc  = (const float*)d_in[10];
  float* out = (float*)d_out;

  unsigned short* wfrag = (unsigned short*)d_ws;       // 64 KB
  unsigned short* wlstm = wfrag + 4096 * 8;            // 128 KB
  unsigned short* xbf   = wlstm + 8192 * 8;            // 16.78 MB

  k0_conv<<<48, 256, 0, stream>>>(W0, Wfw, Wbw, wfrag, wlstm);
  k_dense_ln<<<2048, 256, 0, stream>>>(obs, wfrag, b0, gam, bet, xbf);
  k_lstm<<<512, 256, 0, stream>>>(xbf, wlstm, bfw, bbw, Wc, bc, out);
}

// Round 17
// 97.528 us; speedup vs baseline: 6.2127x; 1.0108x over previous
//
#include <hip/hip_runtime.h>
#include <hip/hip_bf16.h>

typedef __attribute__((ext_vector_type(8))) short bf16x8;
typedef __attribute__((ext_vector_type(4))) float f32x4;

#define MFMA_BF16 __builtin_amdgcn_mfma_f32_16x16x32_bf16

#define GLDS16(gp, lp)                                                        \
  __builtin_amdgcn_global_load_lds(                                           \
      (const __attribute__((address_space(1))) void*)(gp),                    \
      (__attribute__((address_space(3))) void*)(lp), 16, 0, 0)

__device__ __forceinline__ unsigned pk2(float a, float b) {
  __hip_bfloat162 t = __float22bfloat162_rn(make_float2(a, b));
  return *reinterpret_cast<unsigned*>(&t);
}
__device__ __forceinline__ unsigned short f2bf_hw(float f) {
  __hip_bfloat16 h = __float2bfloat16(f);
  return *reinterpret_cast<unsigned short*>(&h);
}
__device__ __forceinline__ float tanh_f(float x) {
  return 1.f - 2.f * __builtin_amdgcn_rcpf(1.f + __expf(2.f * x));
}

// ---------------------------------------------------------------------------
// k0: one-time weight conversion to frag-major bf16 tables in d_ws. (= R16)
// ---------------------------------------------------------------------------
__global__ void k0_conv(const float* __restrict__ W0, const float* __restrict__ Wfw,
                        const float* __restrict__ Wbw, unsigned short* __restrict__ wfrag,
                        unsigned short* __restrict__ wlstm) {
  int gid = blockIdx.x * 256 + threadIdx.x;
  if (gid < 4096) {
    int f = gid >> 6, l = gid & 63;
    int k0 = (f >> 2) * 32 + ((l >> 4) << 3);
    int n = (f & 3) * 16 + (l & 15);
    bf16x8 v;
#pragma unroll
    for (int j = 0; j < 8; ++j) v[j] = (short)f2bf_hw(W0[(k0 + j) * 64 + n]);
    *(bf16x8*)(wfrag + gid * 8) = v;
  } else if (gid < 12288) {
    int g2 = gid - 4096;
    const float* W = (g2 < 4096) ? Wfw : Wbw;
    int f = (g2 & 4095) >> 6, l = g2 & 63;
    int wv = f >> 4, gate = (f >> 2) & 3, kf = f & 3;
    int col = gate * 64 + wv * 16 + (l & 15);
    int kr = kf * 32 + ((l >> 4) << 3);
    bf16x8 v;
#pragma unroll
    for (int j = 0; j < 8; ++j) v[j] = (short)f2bf_hw(W[(kr + j) * 256 + col]);
    *(bf16x8*)(wlstm + g2 * 8) = v;
  }
}

// ---------------------------------------------------------------------------
// K1: R8/R16 kernel + bijective XCD swizzle (2048 = 8 XCD x 256 tiles):
// tile = (bid&7)*256 + bid>>3 -> each XCD streams one contiguous 64-MB
// region of obs; K2's matching swizzle makes its xbf reads L2-local.
// ---------------------------------------------------------------------------
__global__ __launch_bounds__(256, 3) void k_dense_ln(
    const float* __restrict__ obs, const unsigned short* __restrict__ wfrag,
    const float* __restrict__ b0, const float* __restrict__ gam,
    const float* __restrict__ bet, unsigned short* __restrict__ xout) {
  __shared__ __align__(16) char lds[49152];  // 3 x 16 KB
  const int tid = threadIdx.x, w = tid >> 6, l = tid & 63;
  const int g = l >> 4, c = l & 15;
  const int tile = (blockIdx.x & 7) * 256 + (blockIdx.x >> 3);  // XCD swizzle
  const long blk64 = (long)tile * 64;
  const long rb = blk64 + w * 16;

  float b0v[4], gv[4], bv[4];
#pragma unroll
  for (int nt = 0; nt < 4; ++nt) {
    int col = nt * 16 + c;
    b0v[nt] = b0[col]; gv[nt] = gam[col]; bv[nt] = bet[col];
  }
  const unsigned short* wfl = wfrag + l * 8;
  const char* gB = (const char*)obs + blk64 * 2048;

  const int rlo = w * 4 + g;
  asm volatile("s_waitcnt vmcnt(0)" ::: "memory");

#define K1_STAGE(q)                                                           \
  {                                                                           \
    _Pragma("unroll") for (int i = 0; i < 4; ++i) {                           \
      int row_ = i * 16 + rlo;                                                \
      const char* gp_ = gB + (long)row_ * 2048 + (q) * 256 +                  \
                        (long)((c ^ rlo) * 16);                               \
      char* lp_ = lds + ((q) % 3) * 16384 + (i * 4096 + (w * 64 + l) * 16);   \
      GLDS16(gp_, lp_);                                                       \
    }                                                                         \
  }

  K1_STAGE(0);
  K1_STAGE(1);
  K1_STAGE(2);

  f32x4 acc[4];
#pragma unroll
  for (int nt = 0; nt < 4; ++nt) acc[nt] = (f32x4){0.f, 0.f, 0.f, 0.f};

#pragma unroll
  for (int q = 0; q < 8; ++q) {
    constexpr int VW[8] = {8, 16, 24, 24, 24, 24, 20, 16};
    asm volatile("s_waitcnt vmcnt(%0)" :: "i"(VW[q]) : "memory");
    __builtin_amdgcn_s_barrier();
    __builtin_amdgcn_sched_barrier(0);

    const char* rowb = lds + (q % 3) * 16384 + (w * 16 + c) * 256;
#pragma unroll
    for (int kf = 0; kf < 2; ++kf) {
      int fb = (q * 2 + kf) * 4;
      bf16x8 B0 = *(const bf16x8*)(wfl + (fb + 0) * 512);
      bf16x8 B1 = *(const bf16x8*)(wfl + (fb + 1) * 512);
      bf16x8 B2 = *(const bf16x8*)(wfl + (fb + 2) * 512);
      bf16x8 B3 = *(const bf16x8*)(wfl + (fb + 3) * 512);
      int u0 = kf * 8 + g * 2;
      float4 f0 = *(const float4*)(rowb + ((u0 + 0) ^ c) * 16);
      float4 f1 = *(const float4*)(rowb + ((u0 + 1) ^ c) * 16);
      union { bf16x8 v; unsigned u[4]; } af;
      af.u[0] = pk2(f0.x, f0.y); af.u[1] = pk2(f0.z, f0.w);
      af.u[2] = pk2(f1.x, f1.y); af.u[3] = pk2(f1.z, f1.w);
      acc[0] = MFMA_BF16(af.v, B0, acc[0], 0, 0, 0);
      acc[1] = MFMA_BF16(af.v, B1, acc[1], 0, 0, 0);
      acc[2] = MFMA_BF16(af.v, B2, acc[2], 0, 0, 0);
      acc[3] = MFMA_BF16(af.v, B3, acc[3], 0, 0, 0);
    }
    if (q < 5) {
      __builtin_amdgcn_s_barrier();
      __builtin_amdgcn_sched_barrier(0);
      K1_STAGE(q + 3);
    }
  }

  float vv[4][4], s1[4], s2[4];
#pragma unroll
  for (int r = 0; r < 4; ++r) { s1[r] = 0.f; s2[r] = 0.f; }
#pragma unroll
  for (int nt = 0; nt < 4; ++nt)
#pragma unroll
    for (int r = 0; r < 4; ++r) {
      float val = acc[nt][r] + b0v[nt];
      vv[nt][r] = val; s1[r] += val; s2[r] += val * val;
    }
#pragma unroll
  for (int r = 0; r < 4; ++r) {
#pragma unroll
    for (int m = 1; m <= 8; m <<= 1) {
      s1[r] += __shfl_xor(s1[r], m);
      s2[r] += __shfl_xor(s2[r], m);
    }
  }
  unsigned short* xw = (unsigned short*)lds + w * 1024;
#pragma unroll
  for (int r = 0; r < 4; ++r) {
    float mu = s1[r] * 0.015625f;
    float var = s2[r] * 0.015625f - mu * mu;
    float inv = rsqrtf(var + 1e-12f);
    int row = g * 4 + r;
#pragma unroll
    for (int nt = 0; nt < 4; ++nt) {
      float xn = (vv[nt][r] - mu) * inv * gv[nt] + bv[nt];
      xw[(row * 64 + nt * 16 + c) ^ (g << 3)] = f2bf_hw(fmaxf(xn, 0.f));
    }
  }
#pragma unroll
  for (int m2 = 0; m2 < 2; ++m2) {
    int m = m2 * 64 + l;
    int row = m >> 3, u8 = m & 7;
    bf16x8 v = *(const bf16x8*)(xw + ((row * 64 + u8 * 8) ^ ((row >> 2) << 3)));
    *(bf16x8*)(xout + (rb + row) * 64 + u8 * 8) = v;
  }
}

// ---------------------------------------------------------------------------
// K2: R16 kernel + matching XCD swizzle: block bid -> xcd = bid&7,
// k = bid>>3; dir = k&1, seq-group g2 = xcd*32 + (k>>1). K2's block lands
// on the XCD whose L2 holds the K1-produced rows for g2 (2.1 MB/XCD), and
// both dirs of one g2 share an XCD (second dir reads L2-hot x).
// ---------------------------------------------------------------------------
__global__ __launch_bounds__(256, 2) void k_lstm(
    const unsigned short* __restrict__ x, const unsigned short* __restrict__ wlstm,
    const float* __restrict__ bfw, const float* __restrict__ bbw,
    const float* __restrict__ Wc, const float* __restrict__ bc,
    float* __restrict__ out) {
  __shared__ __align__(16) char xl[65536];   // 32 slots x 2KB: x(t), then h(t)
  __shared__ unsigned short hl[2 * 1024];
  const int tid = threadIdx.x, w = tid >> 6, l = tid & 63;
  const int g = l >> 4, c = l & 15;
  const int bid = blockIdx.x;
  const int kk = bid >> 3;
  const int dir = kk & 1;
  const int g2 = (bid & 7) * 32 + (kk >> 1);   // 0..255, XCD-matched to K1
  const int sq = g2 * 16;
  const float* bias = dir ? bbw : bfw;

  bf16x8 Bf[4][4];
  const unsigned short* wl = wlstm + ((long)dir * 4096 + w * 16 * 64) * 8;
#pragma unroll
  for (int gate = 0; gate < 4; ++gate)
#pragma unroll
    for (int kf = 0; kf < 4; ++kf)
      Bf[gate][kf] = *(const bf16x8*)(wl + ((gate * 4 + kf) * 64 + l) * 8);
  float bz[4];
#pragma unroll
  for (int gate = 0; gate < 4; ++gate) bz[gate] = bias[gate * 64 + w * 16 + c];

  bf16x8 Pc[2];
#pragma unroll
  for (int kf = 0; kf < 2; ++kf)
#pragma unroll
    for (int j = 0; j < 8; ++j) Pc[kf][j] = 0;
  float bcv = 0.f;
  if (c < 8) {
#pragma unroll
    for (int kf = 0; kf < 2; ++kf)
#pragma unroll
      for (int j = 0; j < 8; ++j)
        Pc[kf][j] = (short)f2bf_hw(Wc[(kf * 32 + g * 8 + j) * 8 + c]);
    bcv = bc[c];
  }

  asm volatile("s_waitcnt vmcnt(0)" ::: "memory");

  const int ss = l >> 3, sc = l & 7;
#pragma unroll
  for (int j = 0; j < 8; ++j) {
    int tt = w * 8 + j;
    int te = dir ? 31 - tt : tt;
#pragma unroll
    for (int p = 0; p < 2; ++p) {
      int s = p * 8 + ss;
      const char* gp = (const char*)x +
          ((long)(sq + s) * 32 + te) * 128 + (long)(sc ^ (s & 7)) * 16;
      char* lp = xl + tt * 2048 + p * 1024;
      GLDS16(gp, lp);
    }
  }

  for (int i = tid; i < 1024; i += 256) ((unsigned*)hl)[i] = 0u;
  float cs[4] = {0.f, 0.f, 0.f, 0.f};

  if (w == 0) asm volatile("s_waitcnt vmcnt(12)" ::: "memory");
  asm volatile("s_waitcnt lgkmcnt(0)" ::: "memory");
  __builtin_amdgcn_s_barrier();
  __builtin_amdgcn_sched_barrier(0);

  const int hq = w >> 1;
  const int hgp = ((w & 1) * 2 + (c >> 3)) * 16;
  const int hlo = c & 7;

  f32x4 accx[4];
  {
    const char* xt = xl + 0 * 2048 + c * 128;
    bf16x8 Ax0 = *(const bf16x8*)(xt + (long)((g) ^ (c & 7)) * 16);
    bf16x8 Ax1 = *(const bf16x8*)(xt + (long)((4 + g) ^ (c & 7)) * 16);
#pragma unroll
    for (int gate = 0; gate < 4; ++gate) {
      f32x4 b = (f32x4){bz[gate], bz[gate], bz[gate], bz[gate]};
      accx[gate] = MFMA_BF16(Ax1, Bf[gate][1],
                             MFMA_BF16(Ax0, Bf[gate][0], b, 0, 0, 0), 0, 0, 0);
    }
  }
  // close the t=0 hazard window (h(0) overwrites slot 0 at step 0)
  asm volatile("s_waitcnt lgkmcnt(0)" ::: "memory");
  __builtin_amdgcn_s_barrier();
  __builtin_amdgcn_sched_barrier(0);

  int p = 0;
#pragma unroll
  for (int t = 0; t < 32; ++t) {
    bf16x8 Ah0 = *(const bf16x8*)((const char*)hl + p * 2048 + l * 16);
    bf16x8 Ah1 = *(const bf16x8*)((const char*)hl + p * 2048 + 1024 + l * 16);

    f32x4 acc[4];
#pragma unroll
    for (int gate = 0; gate < 4; ++gate)
      acc[gate] = MFMA_BF16(Ah1, Bf[gate][3],
                            MFMA_BF16(Ah0, Bf[gate][2], accx[gate], 0, 0, 0),
                            0, 0, 0);

    if (t + 1 < 32) {
      const char* xt = xl + (t + 1) * 2048 + c * 128;
      bf16x8 Ax0 = *(const bf16x8*)(xt + (long)((g) ^ (c & 7)) * 16);
      bf16x8 Ax1 = *(const bf16x8*)(xt + (long)((4 + g) ^ (c & 7)) * 16);
#pragma unroll
      for (int gate = 0; gate < 4; ++gate) {
        f32x4 b = (f32x4){bz[gate], bz[gate], bz[gate], bz[gate]};
        accx[gate] = MFMA_BF16(Ax1, Bf[gate][1],
                               MFMA_BF16(Ax0, Bf[gate][0], b, 0, 0, 0), 0, 0, 0);
      }
    }

    const int wb = (p ^ 1) * 1024;
    unsigned short* xh = (unsigned short*)xl + t * 1024;
#pragma unroll
    for (int r = 0; r < 4; ++r) {
      float ei = __expf(-acc[0][r]);
      float ej = __expf(2.f * acc[1][r]);
      float ef = __expf(-(acc[2][r] + 1.f));
      float eo = __expf(-acc[3][r]);
      float p12 = (1.f + ei) * (1.f + ej);
      float r3 = __builtin_amdgcn_rcpf(p12 * (1.f + ef));
      float it = (ej - 1.f) * (1.f + ef) * r3;
      float sf = p12 * r3;
      cs[r] = cs[r] * sf + it;
      float ec = __expf(2.f * cs[r]);
      float r2 = __builtin_amdgcn_rcpf((1.f + eo) * (1.f + ec));
      unsigned short hb = f2bf_hw((ec - 1.f) * r2);
      int off = (hq * 64 + hgp + 4 * g + r) * 8 + hlo;
      hl[wb + off] = hb;
      xh[off] = hb;
    }

    if (t + 2 < 32) {
      if (w == ((t + 2) >> 3))
        asm volatile("s_waitcnt vmcnt(%0)" :: "i"(14 - 2 * ((t + 2) & 7)) : "memory");
    }
    asm volatile("s_waitcnt lgkmcnt(0)" ::: "memory");
    __builtin_amdgcn_s_barrier();
    __builtin_amdgcn_sched_barrier(0);
    p ^= 1;
  }

  // parallel projection epilogue: wave w projects timesteps w*8..w*8+7
#pragma unroll
  for (int j = 0; j < 8; ++j) {
    int t = w * 8 + j;
    const char* hb = xl + t * 2048;
    bf16x8 Ph0 = *(const bf16x8*)(hb + l * 16);
    bf16x8 Ph1 = *(const bf16x8*)(hb + 1024 + l * 16);
    f32x4 pa = (f32x4){0.f, 0.f, 0.f, 0.f};
    pa = MFMA_BF16(Ph0, Pc[0], pa, 0, 0, 0);
    pa = MFMA_BF16(Ph1, Pc[1], pa, 0, 0, 0);
    if (c < 8) {
      int tp = dir ? 31 - t : t;
#pragma unroll
      for (int r = 0; r < 4; ++r) {
        long orow = (long)dir * 4096 + sq + 4 * g + r;
        out[(orow * 32 + tp) * 8 + c] = tanh_f(pa[r] + bcv);
      }
    }
  }
}

extern "C" void kernel_launch(void* const* d_in, const int* in_sizes, int n_in,
                              void* d_out, int out_size, void* d_ws, size_t ws_size,
                              hipStream_t stream) {
  const float* obs = (const float*)d_in[0];
  const float* W0  = (const float*)d_in[1];
  const float* b0  = (const float*)d_in[2];
  const float* gam = (const float*)d_in[3];
  const float* bet = (const float*)d_in[4];
  const float* Wfw = (const float*)d_in[5];
  const float* bfw = (const float*)d_in[6];
  const float* Wbw = (const float*)d_in[7];
  const float* bbw = (const float*)d_in[8];
  const float* Wc  = (const float*)d_in[9];
  const float* bc  = (const float*)d_in[10];
  float* out = (float*)d_out;

  unsigned short* wfrag = (unsigned short*)d_ws;       // 64 KB
  unsigned short* wlstm = wfrag + 4096 * 8;            // 128 KB
  unsigned short* xbf   = wlstm + 8192 * 8;            // 16.78 MB

  k0_conv<<<48, 256, 0, stream>>>(W0, Wfw, Wbw, wfrag, wlstm);
  k_dense_ln<<<2048, 256, 0, stream>>>(obs, wfrag, b0, gam, bet, xbf);
  k_lstm<<<512, 256, 0, stream>>>(xbf, wlstm, bfw, bbw, Wc, bc, out);
}